// Round 6
// baseline (1114.506 us; speedup 1.0000x reference)
//
#include <hip/hip_runtime.h>
#include <math.h>

typedef unsigned short u16;
typedef unsigned int   u32;

#define HDIM 96
#define SDIM 48
#define FDIM 24
#define KA   312      // 2H + 2S + F
#define WATT 192
#define KG   288      // 3H

#define KT_A  10      // edge K-steps of 32 (K padded 312 -> 320)
#define KT_G  9       // node K-steps (288)
#define NS    296     // node LDS row stride in u16 (592 B = 37 uint4)

#define NFRAG (2 * KT_A * 12 * 64)   // edge W1 fragments (uint4 count) = 15360
#define W1F_Q (KT_G * 18 * 64)       // 10368 uint4 per node W1
#define W2F_Q (KT_G * 6 * 64)        //  3456 uint4 per node W2
#define NODEF_Q (3 * (W1F_Q + W2F_Q))

// prep_all block partition
#define PB_EDGE 60                   // NFRAG/256
#define PB_W1   41                   // ceil(10368/256)
#define PB_W2   14                   // ceil(3456/256)
#define PB_NODE (3 * (PB_W1 + PB_W2))  // 165

typedef __attribute__((ext_vector_type(8))) __bf16 bf16x8;
typedef __attribute__((ext_vector_type(4))) float  f32x4;

__device__ __forceinline__ u16 f2bf(float f) {
  u32 u = __float_as_uint(f);
  u = (u + 0x7FFFu + ((u >> 16) & 1u)) >> 16;   // RNE
  return (u16)u;
}
__device__ __forceinline__ float bf2f(u16 v) {
  return __uint_as_float((u32)v << 16);
}
__device__ __forceinline__ u32 pack2(float a, float b) {
  return (u32)f2bf(a) | ((u32)f2bf(b) << 16);
}
__device__ __forceinline__ f32x4 mfma_bf16(bf16x8 a, bf16x8 b, f32x4 c) {
  return __builtin_amdgcn_mfma_f32_16x16x32_bf16(a, b, c, 0, 0, 0);
}

// ===========================================================================
// prep_all: single launch doing all weight/activation conversion.
// blocks [0,60): edge W1 -> Bfrag (rev permutation folded, K pad 312->320)
// blocks [60,225): node W1/W2 x3 -> NodeF fragments
// blocks [225,...): x/xs fp32 -> bf16
// ===========================================================================
__global__ __launch_bounds__(256) void prep_all(
    const float* __restrict__ fW1, const float* __restrict__ rW1,
    uint4* __restrict__ Bfrag,
    const float* __restrict__ W1r, const float* __restrict__ W2r,
    const float* __restrict__ W1u, const float* __restrict__ W2u,
    const float* __restrict__ W1c, const float* __restrict__ W2c,
    uint4* __restrict__ NodeF,
    const float* __restrict__ x, const float* __restrict__ xs,
    u32* __restrict__ xb, u32* __restrict__ xsb, int N)
{
  int b = blockIdx.x;
  const int tid = threadIdx.x;

  if (b < PB_EDGE) {                       // ---- edge W1 fragments ----
    const int idx = b * 256 + tid;
    const int lane = idx & 63;
    const int frag = idx >> 6;
    const int nt   = frag % 12;
    const int rest = frag / 12;
    const int kt   = rest % KT_A;
    const int mlp  = rest / KT_A;
    const int q = lane >> 4, c = lane & 15;
    const int n  = nt * 16 + c;
    const int p0 = kt * 16 + q * 4;
    const float* W = mlp ? rW1 : fW1;
    u32 v[4];
#pragma unroll
    for (int w = 0; w < 4; ++w) {
      const int p = p0 + w;
      u32 val = 0u;
      if (p < 156) {
        int src = p;
        if (mlp) {
          if (src < 48)       src += 48;
          else if (src < 96)  src -= 48;
          else if (src < 120) src += 24;
          else if (src < 144) src -= 24;
        }
        const float2 wv = *(const float2*)(W + (size_t)n * KA + 2 * src);
        val = pack2(wv.x, wv.y);
      }
      v[w] = val;
    }
    Bfrag[idx] = make_uint4(v[0], v[1], v[2], v[3]);
    return;
  }
  b -= PB_EDGE;

  if (b < PB_NODE) {                       // ---- node weight fragments ----
    const int mlp = b / (PB_W1 + PB_W2);
    const int lb  = b % (PB_W1 + PB_W2);
    const float* W;
    uint4* o;
    int NT, idx;
    if (lb < PB_W1) {
      NT = 18; idx = lb * 256 + tid;
      W = (mlp == 0) ? W1r : (mlp == 1) ? W1u : W1c;
      o = NodeF + (size_t)mlp * (W1F_Q + W2F_Q);
    } else {
      NT = 6; idx = (lb - PB_W1) * 256 + tid;
      W = (mlp == 0) ? W2r : (mlp == 1) ? W2u : W2c;
      o = NodeF + (size_t)mlp * (W1F_Q + W2F_Q) + W1F_Q;
    }
    if (idx >= KT_G * NT * 64) return;
    const int lane = idx & 63;
    const int frag = idx >> 6;
    const int nt = frag % NT, kt = frag / NT;
    const int q = lane >> 4, c = lane & 15;
    const int n = nt * 16 + c;
    const int k0 = kt * 32 + q * 8;
    u32 v[4];
#pragma unroll
    for (int w = 0; w < 4; ++w) {
      const float2 wv = *(const float2*)(W + (size_t)n * KG + k0 + 2 * w);
      v[w] = pack2(wv.x, wv.y);
    }
    o[idx] = make_uint4(v[0], v[1], v[2], v[3]);
    return;
  }
  b -= PB_NODE;

  {                                        // ---- x / xs -> bf16 ----
    const int i = b * 256 + tid;
    const int nx = N * 48;
    if (i < nx) {
      const float2 v = ((const float2*)x)[i];
      xb[i] = pack2(v.x, v.y);
    } else if (i < nx + N * 24) {
      const float2 v = ((const float2*)xs)[i - nx];
      xsb[i - nx] = pack2(v.x, v.y);
    }
  }
}

// ===========================================================================
// Edge kernel v4: 512 threads (8 waves), 64 edges/block. Direct-global A
// (no LDS A-tile): every 8-bf16 fragment chunk lies in one source region.
// MLP split ACROSS WAVES: waves 0-3 = fwd (N-tiles 3w..3w+2), waves 4-7 =
// rev. One acc[4][3] per thread (48 f32) -> ~4 waves/SIMD occupancy.
// rev input-permutation lives in rev's B fragments. One __syncthreads.
// ===========================================================================
__global__ __launch_bounds__(512, 4) void edge_kernel(
    const u32* __restrict__ xb, const u32* __restrict__ xsb,
    const float* __restrict__ ef, const int* __restrict__ ei,
    const u16* __restrict__ Bfrag,
    const float* __restrict__ fb1, const float* __restrict__ fW2,
    const float* __restrict__ fb2,
    const float* __restrict__ rb1, const float* __restrict__ rW2,
    const float* __restrict__ rb2,
    float* __restrict__ pe, float* __restrict__ out_revw, int N, int E)
{
  __shared__ float red[2][4][64];

  const int tid  = threadIdx.x;
  const int wave = tid >> 6, lane = tid & 63;
  const int mlp  = wave >> 2;          // 0 = fwd, 1 = rev
  const int w4   = wave & 3;
  const int q = lane >> 4, c = lane & 15;
  const int e0 = blockIdx.x * 64;

  // edge ids + endpoints for my 4 M-tiles (row c of each tile)
  int em[4], sm[4], dm[4];
#pragma unroll
  for (int m = 0; m < 4; ++m) {
    em[m] = min(e0 + m * 16 + c, E - 1);
    int s = ei[em[m]], d = ei[(size_t)E + em[m]];
    sm[m] = min(max(s, 0), N - 1);
    dm[m] = min(max(d, 0), N - 1);
  }

  const bf16x8* __restrict__ Bf = (const bf16x8*)Bfrag;

  f32x4 acc[4][3];
#pragma unroll
  for (int m = 0; m < 4; ++m)
    for (int t = 0; t < 3; ++t)
      acc[m][t] = (f32x4){0.f, 0.f, 0.f, 0.f};

#pragma unroll
  for (int kt = 0; kt < KT_A; ++kt) {
    const int p0 = kt * 16 + q * 4;          // u32-pair index of chunk start
    bf16x8 a[4];
#pragma unroll
    for (int m = 0; m < 4; ++m) {
      uint4 av;
      if (kt < 3) {
        av = *(const uint4*)(xb + (size_t)sm[m] * 48 + p0);
      } else if (kt < 6) {
        av = *(const uint4*)(xb + (size_t)dm[m] * 48 + (p0 - 48));
      } else if (kt == 6) {
        av = *(const uint4*)(xsb + (size_t)sm[m] * 24 + (p0 - 96));
      } else if (kt == 7) {
        const u32* p = (q < 2) ? xsb + (size_t)sm[m] * 24 + (p0 - 96)
                               : xsb + (size_t)dm[m] * 24 + (p0 - 120);
        av = *(const uint4*)p;
      } else if (kt == 8) {
        av = *(const uint4*)(xsb + (size_t)dm[m] * 24 + (p0 - 120));
      } else {
        if (q < 3) {
          const float* efp = ef + (size_t)em[m] * 24 + (p0 - 144) * 2;
          const float4 f0 = *(const float4*)efp;
          const float4 f1 = *(const float4*)(efp + 4);
          av = make_uint4(pack2(f0.x, f0.y), pack2(f0.z, f0.w),
                          pack2(f1.x, f1.y), pack2(f1.z, f1.w));
        } else {
          av = make_uint4(0u, 0u, 0u, 0u);   // K-pad (B is zero there too)
        }
      }
      a[m] = __builtin_bit_cast(bf16x8, av);
    }
#pragma unroll
    for (int t = 0; t < 3; ++t) {
      const bf16x8 b = Bf[(((mlp * KT_A + kt) * 12) + w4 * 3 + t) * 64 + lane];
#pragma unroll
      for (int m = 0; m < 4; ++m)
        acc[m][t] = mfma_bf16(a[m], b, acc[m][t]);
    }
  }

  // ---- epilogue: bias + relu + dot(W2), reduce across 16 col-lanes ----
  const float* b1p = mlp ? rb1 : fb1;
  const float* W2p = mlp ? rW2 : fW2;
  float p[4][4];
#pragma unroll
  for (int m = 0; m < 4; ++m)
    for (int r = 0; r < 4; ++r) p[m][r] = 0.f;
#pragma unroll
  for (int t = 0; t < 3; ++t) {
    const int n = (w4 * 3 + t) * 16 + c;
    const float b1f = b1p[n];
    const float w2f = W2p[n];
#pragma unroll
    for (int m = 0; m < 4; ++m)
      for (int r = 0; r < 4; ++r) {
        float h = acc[m][t][r] + b1f;
        h = h > 0.f ? h : 0.f;
        p[m][r] += h * w2f;
      }
  }
  for (int off = 1; off <= 8; off <<= 1)
#pragma unroll
    for (int m = 0; m < 4; ++m)
      for (int r = 0; r < 4; ++r)
        p[m][r] += __shfl_xor(p[m][r], off, 64);

  if (c == 0) {
#pragma unroll
    for (int m = 0; m < 4; ++m)
      for (int r = 0; r < 4; ++r)
        red[mlp][w4][m * 16 + q * 4 + r] = p[m][r];
  }
  __syncthreads();

  if (tid < 64 && e0 + tid < E) {
    const int e = e0 + tid;
    float rawf = red[0][0][tid] + red[0][1][tid] + red[0][2][tid] + red[0][3][tid];
    rawf += fb2[0];
    const float lr = rawf > 0.f ? rawf : 0.01f * rawf;     // leaky_relu
    pe[e] = __expf(lr * 0.10206207261596575f);             // /sqrt(96)
    float rawr = red[1][0][tid] + red[1][1][tid] + red[1][2][tid] + red[1][3][tid];
    rawr += rb2[0];
    out_revw[e] = 1.f / (1.f + __expf(-rawr));
  }
}

// ===========================================================================
// CSR build.
// ===========================================================================
__global__ __launch_bounds__(256) void k_hist(
    const int* __restrict__ ei, int* __restrict__ deg_d,
    int* __restrict__ deg_s, int N, int E)
{
  const int e = blockIdx.x * 256 + threadIdx.x;
  if (e >= E) return;
  const int s = min(max(ei[e], 0), N - 1);
  const int d = min(max(ei[(size_t)E + e], 0), N - 1);
  atomicAdd(&deg_d[d], 1);
  atomicAdd(&deg_s[s], 1);
}

__global__ __launch_bounds__(256) void k_scan1(
    const int* __restrict__ deg_d, const int* __restrict__ deg_s,
    int* __restrict__ start_d, int* __restrict__ start_s,
    int* __restrict__ bsum_d, int* __restrict__ bsum_s, int N)
{
  __shared__ int sh[256];
  const int t = threadIdx.x, i = blockIdx.x * 256 + t;
  {
    const int v = (i < N) ? deg_d[i] : 0;
    sh[t] = v; __syncthreads();
    for (int off = 1; off < 256; off <<= 1) {
      const int u = (t >= off) ? sh[t - off] : 0;
      __syncthreads();
      sh[t] += u;
      __syncthreads();
    }
    if (i < N) start_d[i] = sh[t] - v;
    if (t == 255) bsum_d[blockIdx.x] = sh[255];
    __syncthreads();
  }
  {
    const int v = (i < N) ? deg_s[i] : 0;
    sh[t] = v; __syncthreads();
    for (int off = 1; off < 256; off <<= 1) {
      const int u = (t >= off) ? sh[t - off] : 0;
      __syncthreads();
      sh[t] += u;
      __syncthreads();
    }
    if (i < N) start_s[i] = sh[t] - v;
    if (t == 255) bsum_s[blockIdx.x] = sh[255];
  }
}

// scan2 folded in: each block sums bsum[0..blockIdx) itself (raw block sums).
__global__ __launch_bounds__(256) void k_scan3(
    int* __restrict__ start_d, int* __restrict__ start_s,
    const int* __restrict__ bsum_d, const int* __restrict__ bsum_s,
    int* __restrict__ pos_d, int* __restrict__ pos_s, int N)
{
  __shared__ int offs[2];
  const int t = threadIdx.x;
  if (t < 2) {
    const int* bs = t ? bsum_s : bsum_d;
    int r = 0;
    for (int bb = 0; bb < (int)blockIdx.x; ++bb) r += bs[bb];
    offs[t] = r;
  }
  __syncthreads();
  const int i = blockIdx.x * 256 + t;
  if (i >= N) return;
  const int vd = start_d[i] + offs[0]; start_d[i] = vd; pos_d[i] = vd;
  const int vs = start_s[i] + offs[1]; start_s[i] = vs; pos_s[i] = vs;
}

__global__ __launch_bounds__(256) void k_fill(
    const int* __restrict__ ei, int* __restrict__ pos_d,
    int* __restrict__ pos_s, int* __restrict__ eidx_d,
    int* __restrict__ eidx_s, int N, int E)
{
  const int e = blockIdx.x * 256 + threadIdx.x;
  if (e >= E) return;
  const int s = min(max(ei[e], 0), N - 1);
  const int d = min(max(ei[(size_t)E + e], 0), N - 1);
  eidx_d[atomicAdd(&pos_d[d], 1)] = e;
  eidx_s[atomicAdd(&pos_s[s], 1)] = e;
}

// ===========================================================================
// Gather-aggregate, both directions in one launch (block range split).
// ===========================================================================
__global__ __launch_bounds__(256) void k_agg_all(
    const float* __restrict__ x, const int* __restrict__ ei,
    const float* __restrict__ pe, const float* __restrict__ revw,
    const int* __restrict__ start_d, const int* __restrict__ end_d,
    const int* __restrict__ eidx_d,
    const int* __restrict__ start_s, const int* __restrict__ end_s,
    const int* __restrict__ eidx_s,
    u16* __restrict__ fwdm, u16* __restrict__ revm,
    float* __restrict__ out_fwdw, int N, int E, int ablk)
{
  int b = blockIdx.x;
  const int dir = (b >= ablk) ? 1 : 0;
  if (dir) b -= ablk;
  const int g = threadIdx.x >> 5;
  const int l = threadIdx.x & 31;
  const int n = b * 8 + g;
  if (n >= N) return;

  const int* start = dir ? start_s : start_d;
  const int* endp  = dir ? end_s   : end_d;
  const int* eidx  = dir ? eidx_s  : eidx_d;
  const int beg = start[n], end = endp[n];

  float inv = 1.f;
  if (dir == 0) {
    float sum = 0.f;
    for (int i = beg + l; i < end; i += 32) sum += pe[eidx[i]];
    for (int off = 16; off; off >>= 1) sum += __shfl_xor(sum, off, 32);
    inv = 1.f / (sum + 1e-9f);
    for (int i = beg + l; i < end; i += 32) {
      const int e = eidx[i];
      out_fwdw[e] = pe[e] * inv;
    }
  }

  float a0 = 0.f, a1 = 0.f, a2 = 0.f;
  for (int i = beg; i < end; ++i) {
    const int e = eidx[i];
    const float w = (dir == 0) ? pe[e] * inv : revw[e];
    const int o = (dir == 0) ? min(max(ei[e], 0), N - 1)
                             : min(max(ei[(size_t)E + e], 0), N - 1);
    const float* xr = x + (size_t)o * 96;
    a0 += w * xr[l];
    a1 += w * xr[l + 32];
    a2 += w * xr[l + 64];
  }
  u16* orow = (dir ? revm : fwdm) + (size_t)n * 96;
  orow[l] = f2bf(a0); orow[l + 32] = f2bf(a1); orow[l + 64] = f2bf(a2);
}

// ===========================================================================
// Fused node kernel: 64 nodes/block (4 M-tiles), spill-proof gather
// (per-branch straight-line load->store). Reg-resident weight fragments.
// ===========================================================================
__device__ __forceinline__ void node_mlp(
    const u16* __restrict__ Alds, u16* __restrict__ Hlds,
    const bf16x8* __restrict__ W1f, const bf16x8* __restrict__ W2f,
    const float* __restrict__ b1,
    int wave, int lane, int q, int c, int ntc, int ntc2,
    f32x4 (&acc2)[4][2])
{
  f32x4 acc[4][5];
#pragma unroll
  for (int m = 0; m < 4; ++m)
    for (int t = 0; t < 5; ++t) acc[m][t] = (f32x4){0.f, 0.f, 0.f, 0.f};

#pragma unroll
  for (int kt = 0; kt < KT_G; ++kt) {
    bf16x8 a[4];
#pragma unroll
    for (int m = 0; m < 4; ++m)
      a[m] = *(const bf16x8*)&Alds[(m * 16 + c) * NS + kt * 32 + q * 8];
#pragma unroll
    for (int t = 0; t < 5; ++t) {
      if (t < ntc) {
        const int nt = wave + 4 * t;
        const bf16x8 b = W1f[(kt * 18 + nt) * 64 + lane];
#pragma unroll
        for (int m = 0; m < 4; ++m)
          acc[m][t] = mfma_bf16(a[m], b, acc[m][t]);
      }
    }
  }

  __syncthreads();                       // prior Hlds readers done
#pragma unroll
  for (int t = 0; t < 5; ++t) {
    if (t < ntc) {
      const int n = (wave + 4 * t) * 16 + c;
      const float b1f = b1[n];
#pragma unroll
      for (int m = 0; m < 4; ++m)
        for (int r = 0; r < 4; ++r) {
          float h = acc[m][t][r] + b1f;
          h = h > 0.f ? h : 0.f;
          Hlds[(m * 16 + q * 4 + r) * NS + n] = f2bf(h);
        }
    }
  }
  __syncthreads();                       // H complete

#pragma unroll
  for (int m = 0; m < 4; ++m)
    for (int t = 0; t < 2; ++t) acc2[m][t] = (f32x4){0.f, 0.f, 0.f, 0.f};
#pragma unroll
  for (int kt = 0; kt < KT_G; ++kt) {
    bf16x8 a[4];
#pragma unroll
    for (int m = 0; m < 4; ++m)
      a[m] = *(const bf16x8*)&Hlds[(m * 16 + c) * NS + kt * 32 + q * 8];
#pragma unroll
    for (int t = 0; t < 2; ++t) {
      if (t < ntc2) {
        const int nt = wave + 4 * t;
        const bf16x8 b = W2f[(kt * 6 + nt) * 64 + lane];
#pragma unroll
        for (int m = 0; m < 4; ++m)
          acc2[m][t] = mfma_bf16(a[m], b, acc2[m][t]);
      }
    }
  }
}

__global__ __launch_bounds__(256, 2) void node_fused(
    const float* __restrict__ x, const u32* __restrict__ xb,
    const u32* __restrict__ fwdmb, const u32* __restrict__ revmb,
    const uint4* __restrict__ NodeF,
    const float* __restrict__ b1r, const float* __restrict__ b2r,
    const float* __restrict__ b1u, const float* __restrict__ b2u,
    const float* __restrict__ b1c, const float* __restrict__ b2c,
    float* __restrict__ out_r, float* __restrict__ out_z,
    float* __restrict__ out_upd, int N)
{
  __shared__ __align__(16) u16 Alds[64 * NS];   // 37,888 B
  __shared__ __align__(16) u16 Hlds[64 * NS];   // 37,888 B

  const int tid = threadIdx.x;
  const int wave = tid >> 6, lane = tid & 63;
  const int q = lane >> 4, c = lane & 15;
  const int n0 = blockIdx.x * 64;
  const int ntc  = (wave < 2) ? 5 : 4;
  const int ntc2 = (wave < 2) ? 2 : 1;

  // ---- gather A: spill-proof per-branch bursts (u4 map: x|f|r 12 each) ---
  {
    const int nl = tid >> 2, sub = tid & 3;
    const int node = min(n0 + nl, N - 1);
    const uint4* xr = (const uint4*)(xb    + (size_t)node * 48);
    const uint4* fr = (const uint4*)(fwdmb + (size_t)node * 48);
    const uint4* rr = (const uint4*)(revmb + (size_t)node * 48);
    uint4* Arow = (uint4*)&Alds[nl * NS];       // 37 u4/row
    if (sub == 0) {
      uint4 t0 = xr[0], t1 = xr[1], t2 = xr[2], t3 = xr[3], t4 = xr[4],
            t5 = xr[5], t6 = xr[6], t7 = xr[7], t8 = xr[8];
      Arow[0] = t0; Arow[1] = t1; Arow[2] = t2; Arow[3] = t3; Arow[4] = t4;
      Arow[5] = t5; Arow[6] = t6; Arow[7] = t7; Arow[8] = t8;
    } else if (sub == 1) {
      uint4 t0 = xr[9], t1 = xr[10], t2 = xr[11], t3 = fr[0], t4 = fr[1],
            t5 = fr[2], t6 = fr[3], t7 = fr[4], t8 = fr[5];
      Arow[9] = t0; Arow[10] = t1; Arow[11] = t2; Arow[12] = t3;
      Arow[13] = t4; Arow[14] = t5; Arow[15] = t6; Arow[16] = t7;
      Arow[17] = t8;
    } else if (sub == 2) {
      uint4 t0 = fr[6], t1 = fr[7], t2 = fr[8], t3 = fr[9], t4 = fr[10],
            t5 = fr[11], t6 = rr[0], t7 = rr[1], t8 = rr[2];
      Arow[18] = t0; Arow[19] = t1; Arow[20] = t2; Arow[21] = t3;
      Arow[22] = t4; Arow[23] = t5; Arow[24] = t6; Arow[25] = t7;
      Arow[26] = t8;
    } else {
      uint4 t0 = rr[3], t1 = rr[4], t2 = rr[5], t3 = rr[6], t4 = rr[7],
            t5 = rr[8], t6 = rr[9], t7 = rr[10], t8 = rr[11];
      Arow[27] = t0; Arow[28] = t1; Arow[29] = t2; Arow[30] = t3;
      Arow[31] = t4; Arow[32] = t5; Arow[33] = t6; Arow[34] = t7;
      Arow[35] = t8;
    }
  }
  __syncthreads();

  const bf16x8* W1fr = (const bf16x8*)(NodeF);
  const bf16x8* W2fr = (const bf16x8*)(NodeF + W1F_Q);
  const bf16x8* W1fu = (const bf16x8*)(NodeF + W1F_Q + W2F_Q);
  const bf16x8* W2fu = (const bf16x8*)(NodeF + 2 * W1F_Q + W2F_Q);
  const bf16x8* W1fc = (const bf16x8*)(NodeF + 2 * (W1F_Q + W2F_Q));
  const bf16x8* W2fc = (const bf16x8*)(NodeF + 3 * W1F_Q + 2 * W2F_Q);

  f32x4 acc2[4][2];

  // ---- reset gate ----
  node_mlp(Alds, Hlds, W1fr, W2fr, b1r, wave, lane, q, c, ntc, ntc2, acc2);
  float r_reg[2][4][4];
#pragma unroll
  for (int t = 0; t < 2; ++t) {
    if (t < ntc2) {
      const int n2 = (wave + 4 * t) * 16 + c;
      const float b2f = b2r[n2];
#pragma unroll
      for (int m = 0; m < 4; ++m)
        for (int r = 0; r < 4; ++r) {
          const float v = acc2[m][t][r] + b2f;
          const float rv = 1.f / (1.f + __expf(-v));
          r_reg[t][m][r] = rv;
          const int node = n0 + m * 16 + q * 4 + r;
          if (node < N) out_r[(size_t)node * HDIM + n2] = rv;
        }
    }
  }

  // ---- update gate ----
  node_mlp(Alds, Hlds, W1fu, W2fu, b1u, wave, lane, q, c, ntc, ntc2, acc2);
  float z_reg[2][4][4];
#pragma unroll
  for (int t = 0; t < 2; ++t) {
    if (t < ntc2) {
      const int n2 = (wave + 4 * t) * 16 + c;
      const float b2f = b2u[n2];
#pragma unroll
      for (int m = 0; m < 4; ++m)
        for (int r = 0; r < 4; ++r) {
          const float v = acc2[m][t][r] + b2f;
          const float zv = 1.f / (1.f + __expf(-v));
          z_reg[t][m][r] = zv;
          const int node = n0 + m * 16 + q * 4 + r;
          if (node < N) out_z[(size_t)node * HDIM + n2] = zv;
        }
    }
  }

  // ---- apply r to the x-columns of A in place (disjoint coverage) ----
#pragma unroll
  for (int t = 0; t < 2; ++t) {
    if (t < ntc2) {
      const int n2 = (wave + 4 * t) * 16 + c;
#pragma unroll
      for (int m = 0; m < 4; ++m)
        for (int r = 0; r < 4; ++r) {
          const int row = m * 16 + q * 4 + r;
          const int idx = row * NS + n2;
          Alds[idx] = f2bf(bf2f(Alds[idx]) * r_reg[t][m][r]);
        }
    }
  }
  __syncthreads();

  // ---- candidate + GRU update ----
  node_mlp(Alds, Hlds, W1fc, W2fc, b1c, wave, lane, q, c, ntc, ntc2, acc2);
#pragma unroll
  for (int t = 0; t < 2; ++t) {
    if (t < ntc2) {
      const int n2 = (wave + 4 * t) * 16 + c;
      const float b2f = b2c[n2];
#pragma unroll
      for (int m = 0; m < 4; ++m)
        for (int r = 0; r < 4; ++r) {
          const int node = n0 + m * 16 + q * 4 + r;
          if (node < N) {
            const float v = acc2[m][t][r] + b2f;
            const float ct = tanhf(v);
            const float z = z_reg[t][m][r];
            const float xv = x[(size_t)node * HDIM + n2];
            out_upd[(size_t)node * HDIM + n2] = (1.f - z) * xv + z * ct;
          }
        }
    }
  }
}

__global__ void sentinel_kernel(float* out, int n, float val) {
  const int i = blockIdx.x * 256 + threadIdx.x;
  if (i < n) out[i] = val;
}

// ---------------------------------------------------------------------------
extern "C" void kernel_launch(void* const* d_in, const int* in_sizes, int n_in,
                              void* d_out, int out_size, void* d_ws, size_t ws_size,
                              hipStream_t stream) {
  const float* x  = (const float*)d_in[0];
  const float* xs = (const float*)d_in[1];
  const float* ef = (const float*)d_in[2];
  const int*   ei = (const int*)d_in[3];

  const int N = in_sizes[0] / HDIM;
  const int E = in_sizes[3] / 2;

  float* out = (float*)d_out;

  const int NB = (N + 255) / 256;      // scan blocks (<=1024 supported)

  const bool sizes_ok =
      n_in == 24 && NB <= 1024 &&
      in_sizes[0] == N * HDIM && in_sizes[1] == N * SDIM &&
      in_sizes[2] == E * FDIM && in_sizes[3] == 2 * E &&
      in_sizes[4] == WATT * KA && in_sizes[5] == WATT &&
      in_sizes[6] == WATT && in_sizes[7] == 1 &&
      in_sizes[12] == KG * KG && in_sizes[13] == KG &&
      in_sizes[14] == HDIM * KG && in_sizes[15] == HDIM &&
      out_size == 3 * N * HDIM + 2 * E;
  if (!sizes_ok) {
    sentinel_kernel<<<(out_size + 255) / 256, 256, 0, stream>>>(out, out_size, 777.0f);
    return;
  }

  // ws layout (u32 units) — unchanged from R5
  const size_t eA = ((size_t)E + 3) & ~(size_t)3;
  const size_t needed =
      (eA + (size_t)NFRAG * 4 + (size_t)NODEF_Q * 4 +
       (size_t)N * 48 + (size_t)N * 24 + 2 * (size_t)N * 48 +
       6 * (size_t)N + 2048 + 2 * (size_t)E) * 4;
  if (ws_size < needed) {
    sentinel_kernel<<<(out_size + 255) / 256, 256, 0, stream>>>(out, out_size, 12345.0f);
    return;
  }
  float* pe    = (float*)d_ws;
  uint4* Bfrag = (uint4*)((u32*)d_ws + eA);
  uint4* NodeF = Bfrag + NFRAG;
  u32*   xbw   = (u32*)(NodeF + NODEF_Q);
  u32*   xsbw  = xbw + (size_t)N * 48;
  u32*   fwdmb = xsbw + (size_t)N * 24;
  u32*   revmb = fwdmb + (size_t)N * 48;
  int* deg_d   = (int*)(revmb + (size_t)N * 48);
  int* deg_s   = deg_d + N;
  int* start_d = deg_s + N;
  int* start_s = start_d + N;
  int* pos_d   = start_s + N;
  int* pos_s   = pos_d + N;
  int* bsum_d  = pos_s + N;
  int* bsum_s  = bsum_d + 1024;
  int* eidx_d  = bsum_s + 1024;
  int* eidx_s  = eidx_d + E;

  float* out_update = out;                         // [N,96]
  float* out_fwdw   = out + (size_t)N * HDIM;      // [E]
  float* out_revw   = out_fwdw + E;                // [E]
  float* out_z      = out_revw + E;                // [N,96]
  float* out_r      = out_z + (size_t)N * HDIM;    // [N,96]

  (void)hipMemsetAsync(deg_d, 0, 2 * (size_t)N * sizeof(int), stream);

  // single merged prep launch (edge W1, node W1/W2 x3, x/xs -> bf16)
  const int prep_blocks = PB_EDGE + PB_NODE + (N * 72 + 255) / 256;
  prep_all<<<prep_blocks, 256, 0, stream>>>(
      (const float*)d_in[4], (const float*)d_in[8], Bfrag,
      (const float*)d_in[12], (const float*)d_in[14],
      (const float*)d_in[16], (const float*)d_in[18],
      (const float*)d_in[20], (const float*)d_in[22], NodeF,
      x, xs, xbw, xsbw, N);

  // CSR build
  const int eblk = (E + 255) / 256;
  k_hist<<<eblk, 256, 0, stream>>>(ei, deg_d, deg_s, N, E);
  k_scan1<<<NB, 256, 0, stream>>>(deg_d, deg_s, start_d, start_s,
                                  bsum_d, bsum_s, N);
  k_scan3<<<NB, 256, 0, stream>>>(start_d, start_s, bsum_d, bsum_s,
                                  pos_d, pos_s, N);
  k_fill<<<eblk, 256, 0, stream>>>(ei, pos_d, pos_s, eidx_d, eidx_s, N, E);

  // edge MLPs (512 threads: waves 0-3 fwd, waves 4-7 rev)
  edge_kernel<<<(E + 63) / 64, 512, 0, stream>>>(
      xbw, xsbw, ef, ei, (const u16*)Bfrag,
      (const float*)d_in[5], (const float*)d_in[6], (const float*)d_in[7],
      (const float*)d_in[9], (const float*)d_in[10], (const float*)d_in[11],
      pe, out_revw, N, E);

  // gather-aggregate (both directions, one launch)
  const int ablk = (N + 7) / 8;
  k_agg_all<<<2 * ablk, 256, 0, stream>>>(
      x, ei, pe, out_revw,
      start_d, pos_d, eidx_d, start_s, pos_s, eidx_s,
      (u16*)fwdmb, (u16*)revmb, out_fwdw, N, E, ablk);

  // fused node MLPs
  const int nblk = (N + 63) / 64;
  node_fused<<<nblk, 256, 0, stream>>>(
      x, xbw, fwdmb, revmb, NodeF,
      (const float*)d_in[13], (const float*)d_in[15],
      (const float*)d_in[17], (const float*)d_in[19],
      (const float*)d_in[21], (const float*)d_in[23],
      out_r, out_z, out_update, N);
}

// Round 7
// 932.254 us; speedup vs baseline: 1.1955x; 1.1955x over previous
//
#include <hip/hip_runtime.h>
#include <math.h>

typedef unsigned short u16;
typedef unsigned int   u32;

#define HDIM 96
#define SDIM 48
#define FDIM 24
#define KA   312      // 2H + 2S + F
#define WATT 192
#define KG   288      // 3H

#define KT_G  9       // node K-steps (288)
#define NS    296     // node LDS row stride in u16 (592 B = 37 uint4)

// edge projection fragments
#define PRJB_Q (4 * 5 * 12 * 64)     // 15360 uint4: 4 tables x 5 kt x 12 nt
#define EFB_Q  (2 * 12 * 64)         //  1536 uint4: 2 mlps x 12 nt (kt=1)
#define EDGEB_Q (PRJB_Q + EFB_Q)     // 16896

#define W1F_Q (KT_G * 18 * 64)       // 10368 uint4 per node W1
#define W2F_Q (KT_G * 6 * 64)        //  3456 uint4 per node W2
#define NODEF_Q (3 * (W1F_Q + W2F_Q))

// prep_all block partition
#define PB_EDGE 66                   // EDGEB_Q/256
#define PB_W1   41                   // ceil(10368/256)
#define PB_W2   14                   // ceil(3456/256)
#define PB_NODE (3 * (PB_W1 + PB_W2))  // 165

// edge_asm LDS strides (u16 units)
#define PSTR_EF 40
#define PSTR_H  200

typedef __attribute__((ext_vector_type(8))) __bf16 bf16x8;
typedef __attribute__((ext_vector_type(4))) float  f32x4;

__device__ __forceinline__ u16 f2bf(float f) {
  u32 u = __float_as_uint(f);
  u = (u + 0x7FFFu + ((u >> 16) & 1u)) >> 16;   // RNE
  return (u16)u;
}
__device__ __forceinline__ float bf2f(u16 v) {
  return __uint_as_float((u32)v << 16);
}
__device__ __forceinline__ float bflo(u32 u) {
  return __uint_as_float(u << 16);
}
__device__ __forceinline__ float bfhi(u32 u) {
  return __uint_as_float(u & 0xffff0000u);
}
__device__ __forceinline__ u32 pack2(float a, float b) {
  return (u32)f2bf(a) | ((u32)f2bf(b) << 16);
}
__device__ __forceinline__ f32x4 mfma_bf16(bf16x8 a, bf16x8 b, f32x4 c) {
  return __builtin_amdgcn_mfma_f32_16x16x32_bf16(a, b, c, 0, 0, 0);
}

// ===========================================================================
// prep_all: single launch doing all weight/activation conversion.
// blocks [0,66): edge projection/ef fragments:
//   PrjB (idx<15360): table tbl in {0:fwd-first,1:fwd-second,2:rev-first,
//   3:rev-second}; K=144 ([x|xs] role columns) padded to 160 (5 kt).
//   EfB (idx>=15360): W1 cols 288..311 (ef), K padded 24->32 (1 kt).
// blocks [66,231): node W1/W2 x3 -> NodeF fragments
// blocks [231,...): x/xs fp32 -> bf16
// ===========================================================================
__global__ __launch_bounds__(256) void prep_all(
    const float* __restrict__ fW1, const float* __restrict__ rW1,
    uint4* __restrict__ EdgeB,
    const float* __restrict__ W1r, const float* __restrict__ W2r,
    const float* __restrict__ W1u, const float* __restrict__ W2u,
    const float* __restrict__ W1c, const float* __restrict__ W2c,
    uint4* __restrict__ NodeF,
    const float* __restrict__ x, const float* __restrict__ xs,
    u32* __restrict__ xb, u32* __restrict__ xsb, int N)
{
  int b = blockIdx.x;
  const int tid = threadIdx.x;

  if (b < PB_EDGE) {
    const int idx = b * 256 + tid;
    const int lane = idx & 63;
    const int q = lane >> 4, c = lane & 15;
    if (idx < PRJB_Q) {                    // ---- projection fragments ----
      const int frag = idx >> 6;
      const int nt   = frag % 12;
      const int rest = frag / 12;          // 0..19
      const int kt   = rest % 5;
      const int tbl  = rest / 5;           // 0..3
      const float* W = (tbl < 2) ? fW1 : rW1;
      const int role = tbl & 1;
      const int n  = nt * 16 + c;
      const int p0 = kt * 16 + q * 4;      // fp32-pair index in [0,80)
      u32 v[4];
#pragma unroll
      for (int w = 0; w < 4; ++w) {
        const int p = p0 + w;
        u32 val = 0u;
        int col = -1;
        if (p < 48)      col = role * 96 + 2 * p;            // x part
        else if (p < 72) col = 192 + role * 48 + 2 * (p - 48); // xs part
        if (col >= 0) {
          const float2 wv = *(const float2*)(W + (size_t)n * KA + col);
          val = pack2(wv.x, wv.y);
        }
        v[w] = val;
      }
      EdgeB[idx] = make_uint4(v[0], v[1], v[2], v[3]);
    } else {                               // ---- ef fragments ----
      const int i2 = idx - PRJB_Q;         // 0..1535 (lane preserved)
      const int f2 = i2 >> 6;
      const int nt = f2 % 12, mlp = f2 / 12;
      const float* W = mlp ? rW1 : fW1;
      const int n  = nt * 16 + c;
      const int p0 = q * 4;                // pair idx in [0,16)
      u32 v[4];
#pragma unroll
      for (int w = 0; w < 4; ++w) {
        const int p = p0 + w;
        u32 val = 0u;
        if (p < 12) {
          const float2 wv = *(const float2*)(W + (size_t)n * KA + 288 + 2 * p);
          val = pack2(wv.x, wv.y);
        }
        v[w] = val;
      }
      EdgeB[idx] = make_uint4(v[0], v[1], v[2], v[3]);
    }
    return;
  }
  b -= PB_EDGE;

  if (b < PB_NODE) {                       // ---- node weight fragments ----
    const int mlp = b / (PB_W1 + PB_W2);
    const int lb  = b % (PB_W1 + PB_W2);
    const float* W;
    uint4* o;
    int NT, idx;
    if (lb < PB_W1) {
      NT = 18; idx = lb * 256 + tid;
      W = (mlp == 0) ? W1r : (mlp == 1) ? W1u : W1c;
      o = NodeF + (size_t)mlp * (W1F_Q + W2F_Q);
    } else {
      NT = 6; idx = (lb - PB_W1) * 256 + tid;
      W = (mlp == 0) ? W2r : (mlp == 1) ? W2u : W2c;
      o = NodeF + (size_t)mlp * (W1F_Q + W2F_Q) + W1F_Q;
    }
    if (idx >= KT_G * NT * 64) return;
    const int lane = idx & 63;
    const int frag = idx >> 6;
    const int nt = frag % NT, kt = frag / NT;
    const int q = lane >> 4, c = lane & 15;
    const int n = nt * 16 + c;
    const int k0 = kt * 32 + q * 8;
    u32 v[4];
#pragma unroll
    for (int w = 0; w < 4; ++w) {
      const float2 wv = *(const float2*)(W + (size_t)n * KG + k0 + 2 * w);
      v[w] = pack2(wv.x, wv.y);
    }
    o[idx] = make_uint4(v[0], v[1], v[2], v[3]);
    return;
  }
  b -= PB_NODE;

  {                                        // ---- x / xs -> bf16 ----
    const int i = b * 256 + tid;
    const int nx = N * 48;
    if (i < nx) {
      const float2 v = ((const float2*)x)[i];
      xb[i] = pack2(v.x, v.y);
    } else if (i < nx + N * 24) {
      const float2 v = ((const float2*)xs)[i - nx];
      xsb[i - nx] = pack2(v.x, v.y);
    }
  }
}

// ===========================================================================
// proj_kernel: 4 node-projection tables [N x 192] bf16.
// tbl0 = fW1 first-arg role, tbl1 = fW1 second-arg, tbl2 = rW1 first-arg,
// tbl3 = rW1 second-arg. A = [x|xs] (K=144 pad 160), direct-global bf16.
// 64 nodes/block, 512 threads: wave -> (tbl = w&3, half = w>>2 -> 6 n-tiles).
// ===========================================================================
__global__ __launch_bounds__(512) void proj_kernel(
    const u32* __restrict__ xb, const u32* __restrict__ xsb,
    const u16* __restrict__ EdgeB, u16* __restrict__ tabs, int N)
{
  const int tid = threadIdx.x;
  const int wave = tid >> 6, lane = tid & 63;
  const int q = lane >> 4, c = lane & 15;
  const int tbl = wave & 3, half = wave >> 2;
  const int n0 = blockIdx.x * 64;

  int nd[4];
#pragma unroll
  for (int m = 0; m < 4; ++m) nd[m] = min(n0 + m * 16 + c, N - 1);

  const bf16x8* __restrict__ Bf = (const bf16x8*)EdgeB;

  f32x4 acc[4][6];
#pragma unroll
  for (int m = 0; m < 4; ++m)
    for (int t = 0; t < 6; ++t) acc[m][t] = (f32x4){0.f, 0.f, 0.f, 0.f};

#pragma unroll
  for (int kt = 0; kt < 5; ++kt) {
    bf16x8 a[4];
#pragma unroll
    for (int m = 0; m < 4; ++m) {
      uint4 av;
      if (kt < 3) {
        av = *(const uint4*)(xb + (size_t)nd[m] * 48 + kt * 16 + q * 4);
      } else if (kt == 3) {
        av = *(const uint4*)(xsb + (size_t)nd[m] * 24 + q * 4);
      } else {
        if (q < 2) av = *(const uint4*)(xsb + (size_t)nd[m] * 24 + 16 + q * 4);
        else       av = make_uint4(0u, 0u, 0u, 0u);
      }
      a[m] = __builtin_bit_cast(bf16x8, av);
    }
#pragma unroll
    for (int t = 0; t < 6; ++t) {
      const int nt = half * 6 + t;
      const bf16x8 bfr = Bf[(((tbl * 5 + kt) * 12) + nt) * 64 + lane];
#pragma unroll
      for (int m = 0; m < 4; ++m)
        acc[m][t] = mfma_bf16(a[m], bfr, acc[m][t]);
    }
  }

  u16* Tp = tabs + (size_t)tbl * N * 192;
#pragma unroll
  for (int t = 0; t < 6; ++t) {
    const int col = (half * 6 + t) * 16 + c;
#pragma unroll
    for (int m = 0; m < 4; ++m)
      for (int r = 0; r < 4; ++r) {
        const int node = n0 + m * 16 + q * 4 + r;
        if (node < N) Tp[(size_t)node * 192 + col] = f2bf(acc[m][t][r]);
      }
  }
}

// ===========================================================================
// edge_asm: per 64-edge block:
// phase 0: ef rows -> LDS bf16 (pad 24->32)
// phase 1: Pef = W1ef @ ef via MFMA (K=32; waves 0-3 fwd, 4-7 rev) -> LDS bf16
// phase 2: thread (el, sub) assembles 24-col slice:
//   fwd: relu(Ap0[s]+Bp0[d]+Pef0+fb1) . fW2 ; rev: relu(Ap1[d]+Bp1[s]+...).rW2
//   8-lane shuffle reduce -> pe[e] (softmax numerator), out_revw[e] (sigmoid).
// ===========================================================================
__device__ __forceinline__ float dot24(
    const u16* __restrict__ Arow, const u16* __restrict__ Brow,
    const u16* __restrict__ Prow,
    const float* __restrict__ b1p, const float* __restrict__ w2p)
{
  float acc = 0.f;
  const uint4* A4 = (const uint4*)Arow;
  const uint4* B4 = (const uint4*)Brow;
  const uint4* P4 = (const uint4*)Prow;
  const float4* b14 = (const float4*)b1p;
  const float4* w24 = (const float4*)w2p;
#pragma unroll
  for (int ch = 0; ch < 3; ++ch) {
    const uint4 aa = A4[ch], bb = B4[ch], pp = P4[ch];
    const float4 b1a = b14[2 * ch], b1b = b14[2 * ch + 1];
    const float4 w2a = w24[2 * ch], w2b = w24[2 * ch + 1];
    const u32 au[4] = {aa.x, aa.y, aa.z, aa.w};
    const u32 bu[4] = {bb.x, bb.y, bb.z, bb.w};
    const u32 pu[4] = {pp.x, pp.y, pp.z, pp.w};
    const float b1s[8] = {b1a.x, b1a.y, b1a.z, b1a.w, b1b.x, b1b.y, b1b.z, b1b.w};
    const float w2s[8] = {w2a.x, w2a.y, w2a.z, w2a.w, w2b.x, w2b.y, w2b.z, w2b.w};
#pragma unroll
    for (int w = 0; w < 4; ++w) {
      float vL = bflo(au[w]) + bflo(bu[w]) + bflo(pu[w]) + b1s[2 * w];
      vL = vL > 0.f ? vL : 0.f;
      acc += vL * w2s[2 * w];
      float vH = bfhi(au[w]) + bfhi(bu[w]) + bfhi(pu[w]) + b1s[2 * w + 1];
      vH = vH > 0.f ? vH : 0.f;
      acc += vH * w2s[2 * w + 1];
    }
  }
  return acc;
}

__global__ __launch_bounds__(512, 4) void edge_asm(
    const float* __restrict__ ef, const int* __restrict__ ei,
    const u16* __restrict__ EdgeB, const u16* __restrict__ tabs,
    const float* __restrict__ fb1, const float* __restrict__ fW2,
    const float* __restrict__ fb2,
    const float* __restrict__ rb1, const float* __restrict__ rW2,
    const float* __restrict__ rb2,
    float* __restrict__ pe, float* __restrict__ out_revw, int N, int E)
{
  __shared__ __align__(16) u16 EfL[64 * PSTR_EF];      //  5,120 B
  __shared__ __align__(16) u16 PefL[2][64 * PSTR_H];   // 51,200 B

  const int tid  = threadIdx.x;
  const int wave = tid >> 6, lane = tid & 63;
  const int q = lane >> 4, c = lane & 15;
  const int mlp = wave >> 2, w4 = wave & 3;
  const int e0 = blockIdx.x * 64;

  // ---- phase 0: ef -> LDS bf16 ----
  if (tid < 384) {
    const int el = tid / 6, part = tid % 6;
    const int e = min(e0 + el, E - 1);
    const float4 f = *(const float4*)(ef + (size_t)e * 24 + part * 4);
    *(uint2*)&EfL[el * PSTR_EF + part * 4] =
        make_uint2(pack2(f.x, f.y), pack2(f.z, f.w));
  } else if (tid < 448) {
    const int el = tid - 384;
    *(uint4*)&EfL[el * PSTR_EF + 24] = make_uint4(0u, 0u, 0u, 0u);
  }
  __syncthreads();

  // ---- phase 1: Pef MFMA (K=32) ----
  {
    const bf16x8* __restrict__ BfAll = (const bf16x8*)EdgeB;
    f32x4 acc[4][3];
#pragma unroll
    for (int m = 0; m < 4; ++m)
      for (int t = 0; t < 3; ++t) acc[m][t] = (f32x4){0.f, 0.f, 0.f, 0.f};
    bf16x8 a[4];
#pragma unroll
    for (int m = 0; m < 4; ++m)
      a[m] = *(const bf16x8*)&EfL[(m * 16 + c) * PSTR_EF + q * 8];
#pragma unroll
    for (int t = 0; t < 3; ++t) {
      const bf16x8 bfr = BfAll[PRJB_Q + ((mlp * 12) + w4 * 3 + t) * 64 + lane];
#pragma unroll
      for (int m = 0; m < 4; ++m)
        acc[m][t] = mfma_bf16(a[m], bfr, acc[m][t]);
    }
#pragma unroll
    for (int m = 0; m < 4; ++m)
      for (int t = 0; t < 3; ++t)
        for (int r = 0; r < 4; ++r)
          PefL[mlp][(m * 16 + q * 4 + r) * PSTR_H + (w4 * 3 + t) * 16 + c] =
              f2bf(acc[m][t][r]);
  }
  __syncthreads();

  // ---- phase 2: assemble + reduce ----
  const int el = tid >> 3, sub = tid & 7;
  const int e  = e0 + el;
  const int ec = min(e, E - 1);
  int s = ei[ec], d = ei[(size_t)E + ec];
  s = min(max(s, 0), N - 1);
  d = min(max(d, 0), N - 1);
  const int off = sub * 24;

  const u16* Ap0 = tabs;
  const u16* Bp0 = tabs + (size_t)N * 192;
  const u16* Ap1 = tabs + 2 * (size_t)N * 192;
  const u16* Bp1 = tabs + 3 * (size_t)N * 192;

  float accf = dot24(Ap0 + (size_t)s * 192 + off, Bp0 + (size_t)d * 192 + off,
                     &PefL[0][el * PSTR_H + off], fb1 + off, fW2 + off);
  float accr = dot24(Ap1 + (size_t)d * 192 + off, Bp1 + (size_t)s * 192 + off,
                     &PefL[1][el * PSTR_H + off], rb1 + off, rW2 + off);

#pragma unroll
  for (int o = 1; o <= 4; o <<= 1) {
    accf += __shfl_xor(accf, o, 64);
    accr += __shfl_xor(accr, o, 64);
  }

  if (sub == 0 && e < E) {
    float rawf = accf + fb2[0];
    const float lr = rawf > 0.f ? rawf : 0.01f * rawf;     // leaky_relu
    pe[e] = __expf(lr * 0.10206207261596575f);             // /sqrt(96)
    float rawr = accr + rb2[0];
    out_revw[e] = 1.f / (1.f + __expf(-rawr));
  }
}

// ===========================================================================
// CSR build (unchanged).
// ===========================================================================
__global__ __launch_bounds__(256) void k_hist(
    const int* __restrict__ ei, int* __restrict__ deg_d,
    int* __restrict__ deg_s, int N, int E)
{
  const int e = blockIdx.x * 256 + threadIdx.x;
  if (e >= E) return;
  const int s = min(max(ei[e], 0), N - 1);
  const int d = min(max(ei[(size_t)E + e], 0), N - 1);
  atomicAdd(&deg_d[d], 1);
  atomicAdd(&deg_s[s], 1);
}

__global__ __launch_bounds__(256) void k_scan1(
    const int* __restrict__ deg_d, const int* __restrict__ deg_s,
    int* __restrict__ start_d, int* __restrict__ start_s,
    int* __restrict__ bsum_d, int* __restrict__ bsum_s, int N)
{
  __shared__ int sh[256];
  const int t = threadIdx.x, i = blockIdx.x * 256 + t;
  {
    const int v = (i < N) ? deg_d[i] : 0;
    sh[t] = v; __syncthreads();
    for (int off = 1; off < 256; off <<= 1) {
      const int u = (t >= off) ? sh[t - off] : 0;
      __syncthreads();
      sh[t] += u;
      __syncthreads();
    }
    if (i < N) start_d[i] = sh[t] - v;
    if (t == 255) bsum_d[blockIdx.x] = sh[255];
    __syncthreads();
  }
  {
    const int v = (i < N) ? deg_s[i] : 0;
    sh[t] = v; __syncthreads();
    for (int off = 1; off < 256; off <<= 1) {
      const int u = (t >= off) ? sh[t - off] : 0;
      __syncthreads();
      sh[t] += u;
      __syncthreads();
    }
    if (i < N) start_s[i] = sh[t] - v;
    if (t == 255) bsum_s[blockIdx.x] = sh[255];
  }
}

__global__ __launch_bounds__(256) void k_scan3(
    int* __restrict__ start_d, int* __restrict__ start_s,
    const int* __restrict__ bsum_d, const int* __restrict__ bsum_s,
    int* __restrict__ pos_d, int* __restrict__ pos_s, int N)
{
  __shared__ int offs[2];
  const int t = threadIdx.x;
  if (t < 2) {
    const int* bs = t ? bsum_s : bsum_d;
    int r = 0;
    for (int bb = 0; bb < (int)blockIdx.x; ++bb) r += bs[bb];
    offs[t] = r;
  }
  __syncthreads();
  const int i = blockIdx.x * 256 + t;
  if (i >= N) return;
  const int vd = start_d[i] + offs[0]; start_d[i] = vd; pos_d[i] = vd;
  const int vs = start_s[i] + offs[1]; start_s[i] = vs; pos_s[i] = vs;
}

__global__ __launch_bounds__(256) void k_fill(
    const int* __restrict__ ei, int* __restrict__ pos_d,
    int* __restrict__ pos_s, int* __restrict__ eidx_d,
    int* __restrict__ eidx_s, int N, int E)
{
  const int e = blockIdx.x * 256 + threadIdx.x;
  if (e >= E) return;
  const int s = min(max(ei[e], 0), N - 1);
  const int d = min(max(ei[(size_t)E + e], 0), N - 1);
  eidx_d[atomicAdd(&pos_d[d], 1)] = e;
  eidx_s[atomicAdd(&pos_s[s], 1)] = e;
}

// ===========================================================================
// Gather-aggregate, both directions in one launch.
// ===========================================================================
__global__ __launch_bounds__(256) void k_agg_all(
    const float* __restrict__ x, const int* __restrict__ ei,
    const float* __restrict__ pe, const float* __restrict__ revw,
    const int* __restrict__ start_d, const int* __restrict__ end_d,
    const int* __restrict__ eidx_d,
    const int* __restrict__ start_s, const int* __restrict__ end_s,
    const int* __restrict__ eidx_s,
    u16* __restrict__ fwdm, u16* __restrict__ revm,
    float* __restrict__ out_fwdw, int N, int E, int ablk)
{
  int b = blockIdx.x;
  const int dir = (b >= ablk) ? 1 : 0;
  if (dir) b -= ablk;
  const int g = threadIdx.x >> 5;
  const int l = threadIdx.x & 31;
  const int n = b * 8 + g;
  if (n >= N) return;

  const int* start = dir ? start_s : start_d;
  const int* endp  = dir ? end_s   : end_d;
  const int* eidx  = dir ? eidx_s  : eidx_d;
  const int beg = start[n], end = endp[n];

  float inv = 1.f;
  if (dir == 0) {
    float sum = 0.f;
    for (int i = beg + l; i < end; i += 32) sum += pe[eidx[i]];
    for (int off = 16; off; off >>= 1) sum += __shfl_xor(sum, off, 32);
    inv = 1.f / (sum + 1e-9f);
    for (int i = beg + l; i < end; i += 32) {
      const int e = eidx[i];
      out_fwdw[e] = pe[e] * inv;
    }
  }

  float a0 = 0.f, a1 = 0.f, a2 = 0.f;
  for (int i = beg; i < end; ++i) {
    const int e = eidx[i];
    const float w = (dir == 0) ? pe[e] * inv : revw[e];
    const int o = (dir == 0) ? min(max(ei[e], 0), N - 1)
                             : min(max(ei[(size_t)E + e], 0), N - 1);
    const float* xr = x + (size_t)o * 96;
    a0 += w * xr[l];
    a1 += w * xr[l + 32];
    a2 += w * xr[l + 64];
  }
  u16* orow = (dir ? revm : fwdm) + (size_t)n * 96;
  orow[l] = f2bf(a0); orow[l + 32] = f2bf(a1); orow[l + 64] = f2bf(a2);
}

// ===========================================================================
// Fused node kernel (unchanged from R5/R6).
// ===========================================================================
__device__ __forceinline__ void node_mlp(
    const u16* __restrict__ Alds, u16* __restrict__ Hlds,
    const bf16x8* __restrict__ W1f, const bf16x8* __restrict__ W2f,
    const float* __restrict__ b1,
    int wave, int lane, int q, int c, int ntc, int ntc2,
    f32x4 (&acc2)[4][2])
{
  f32x4 acc[4][5];
#pragma unroll
  for (int m = 0; m < 4; ++m)
    for (int t = 0; t < 5; ++t) acc[m][t] = (f32x4){0.f, 0.f, 0.f, 0.f};

#pragma unroll
  for (int kt = 0; kt < KT_G; ++kt) {
    bf16x8 a[4];
#pragma unroll
    for (int m = 0; m < 4; ++m)
      a[m] = *(const bf16x8*)&Alds[(m * 16 + c) * NS + kt * 32 + q * 8];
#pragma unroll
    for (int t = 0; t < 5; ++t) {
      if (t < ntc) {
        const int nt = wave + 4 * t;
        const bf16x8 b = W1f[(kt * 18 + nt) * 64 + lane];
#pragma unroll
        for (int m = 0; m < 4; ++m)
          acc[m][t] = mfma_bf16(a[m], b, acc[m][t]);
      }
    }
  }

  __syncthreads();
#pragma unroll
  for (int t = 0; t < 5; ++t) {
    if (t < ntc) {
      const int n = (wave + 4 * t) * 16 + c;
      const float b1f = b1[n];
#pragma unroll
      for (int m = 0; m < 4; ++m)
        for (int r = 0; r < 4; ++r) {
          float h = acc[m][t][r] + b1f;
          h = h > 0.f ? h : 0.f;
          Hlds[(m * 16 + q * 4 + r) * NS + n] = f2bf(h);
        }
    }
  }
  __syncthreads();

#pragma unroll
  for (int m = 0; m < 4; ++m)
    for (int t = 0; t < 2; ++t) acc2[m][t] = (f32x4){0.f, 0.f, 0.f, 0.f};
#pragma unroll
  for (int kt = 0; kt < KT_G; ++kt) {
    bf16x8 a[4];
#pragma unroll
    for (int m = 0; m < 4; ++m)
      a[m] = *(const bf16x8*)&Hlds[(m * 16 + c) * NS + kt * 32 + q * 8];
#pragma unroll
    for (int t = 0; t < 2; ++t) {
      if (t < ntc2) {
        const int nt = wave + 4 * t;
        const bf16x8 b = W2f[(kt * 6 + nt) * 64 + lane];
#pragma unroll
        for (int m = 0; m < 4; ++m)
          acc2[m][t] = mfma_bf16(a[m], b, acc2[m][t]);
      }
    }
  }
}

__global__ __launch_bounds__(256, 2) void node_fused(
    const float* __restrict__ x, const u32* __restrict__ xb,
    const u32* __restrict__ fwdmb, const u32* __restrict__ revmb,
    const uint4* __restrict__ NodeF,
    const float* __restrict__ b1r, const float* __restrict__ b2r,
    const float* __restrict__ b1u, const float* __restrict__ b2u,
    const float* __restrict__ b1c, const float* __restrict__ b2c,
    float* __restrict__ out_r, float* __restrict__ out_z,
    float* __restrict__ out_upd, int N)
{
  __shared__ __align__(16) u16 Alds[64 * NS];
  __shared__ __align__(16) u16 Hlds[64 * NS];

  const int tid = threadIdx.x;
  const int wave = tid >> 6, lane = tid & 63;
  const int q = lane >> 4, c = lane & 15;
  const int n0 = blockIdx.x * 64;
  const int ntc  = (wave < 2) ? 5 : 4;
  const int ntc2 = (wave < 2) ? 2 : 1;

  {
    const int nl = tid >> 2, sub = tid & 3;
    const int node = min(n0 + nl, N - 1);
    const uint4* xr = (const uint4*)(xb    + (size_t)node * 48);
    const uint4* fr = (const uint4*)(fwdmb + (size_t)node * 48);
    const uint4* rr = (const uint4*)(revmb + (size_t)node * 48);
    uint4* Arow = (uint4*)&Alds[nl * NS];
    if (sub == 0) {
      uint4 t0 = xr[0], t1 = xr[1], t2 = xr[2], t3 = xr[3], t4 = xr[4],
            t5 = xr[5], t6 = xr[6], t7 = xr[7], t8 = xr[8];
      Arow[0] = t0; Arow[1] = t1; Arow[2] = t2; Arow[3] = t3; Arow[4] = t4;
      Arow[5] = t5; Arow[6] = t6; Arow[7] = t7; Arow[8] = t8;
    } else if (sub == 1) {
      uint4 t0 = xr[9], t1 = xr[10], t2 = xr[11], t3 = fr[0], t4 = fr[1],
            t5 = fr[2], t6 = fr[3], t7 = fr[4], t8 = fr[5];
      Arow[9] = t0; Arow[10] = t1; Arow[11] = t2; Arow[12] = t3;
      Arow[13] = t4; Arow[14] = t5; Arow[15] = t6; Arow[16] = t7;
      Arow[17] = t8;
    } else if (sub == 2) {
      uint4 t0 = fr[6], t1 = fr[7], t2 = fr[8], t3 = fr[9], t4 = fr[10],
            t5 = fr[11], t6 = rr[0], t7 = rr[1], t8 = rr[2];
      Arow[18] = t0; Arow[19] = t1; Arow[20] = t2; Arow[21] = t3;
      Arow[22] = t4; Arow[23] = t5; Arow[24] = t6; Arow[25] = t7;
      Arow[26] = t8;
    } else {
      uint4 t0 = rr[3], t1 = rr[4], t2 = rr[5], t3 = rr[6], t4 = rr[7],
            t5 = rr[8], t6 = rr[9], t7 = rr[10], t8 = rr[11];
      Arow[27] = t0; Arow[28] = t1; Arow[29] = t2; Arow[30] = t3;
      Arow[31] = t4; Arow[32] = t5; Arow[33] = t6; Arow[34] = t7;
      Arow[35] = t8;
    }
  }
  __syncthreads();

  const bf16x8* W1fr = (const bf16x8*)(NodeF);
  const bf16x8* W2fr = (const bf16x8*)(NodeF + W1F_Q);
  const bf16x8* W1fu = (const bf16x8*)(NodeF + W1F_Q + W2F_Q);
  const bf16x8* W2fu = (const bf16x8*)(NodeF + 2 * W1F_Q + W2F_Q);
  const bf16x8* W1fc = (const bf16x8*)(NodeF + 2 * (W1F_Q + W2F_Q));
  const bf16x8* W2fc = (const bf16x8*)(NodeF + 3 * W1F_Q + 2 * W2F_Q);

  f32x4 acc2[4][2];

  node_mlp(Alds, Hlds, W1fr, W2fr, b1r, wave, lane, q, c, ntc, ntc2, acc2);
  float r_reg[2][4][4];
#pragma unroll
  for (int t = 0; t < 2; ++t) {
    if (t < ntc2) {
      const int n2 = (wave + 4 * t) * 16 + c;
      const float b2f = b2r[n2];
#pragma unroll
      for (int m = 0; m < 4; ++m)
        for (int r = 0; r < 4; ++r) {
          const float v = acc2[m][t][r] + b2f;
          const float rv = 1.f / (1.f + __expf(-v));
          r_reg[t][m][r] = rv;
          const int node = n0 + m * 16 + q * 4 + r;
          if (node < N) out_r[(size_t)node * HDIM + n2] = rv;
        }
    }
  }

  node_mlp(Alds, Hlds, W1fu, W2fu, b1u, wave, lane, q, c, ntc, ntc2, acc2);
  float z_reg[2][4][4];
#pragma unroll
  for (int t = 0; t < 2; ++t) {
    if (t < ntc2) {
      const int n2 = (wave + 4 * t) * 16 + c;
      const float b2f = b2u[n2];
#pragma unroll
      for (int m = 0; m < 4; ++m)
        for (int r = 0; r < 4; ++r) {
          const float v = acc2[m][t][r] + b2f;
          const float zv = 1.f / (1.f + __expf(-v));
          z_reg[t][m][r] = zv;
          const int node = n0 + m * 16 + q * 4 + r;
          if (node < N) out_z[(size_t)node * HDIM + n2] = zv;
        }
    }
  }

#pragma unroll
  for (int t = 0; t < 2; ++t) {
    if (t < ntc2) {
      const int n2 = (wave + 4 * t) * 16 + c;
#pragma unroll
      for (int m = 0; m < 4; ++m)
        for (int r = 0; r < 4; ++r) {
          const int row = m * 16 + q * 4 + r;
          const int idx = row * NS + n2;
          Alds[idx] = f2bf(bf2f(Alds[idx]) * r_reg[t][m][r]);
        }
    }
  }
  __syncthreads();

  node_mlp(Alds, Hlds, W1fc, W2fc, b1c, wave, lane, q, c, ntc, ntc2, acc2);
#pragma unroll
  for (int t = 0; t < 2; ++t) {
    if (t < ntc2) {
      const int n2 = (wave + 4 * t) * 16 + c;
      const float b2f = b2c[n2];
#pragma unroll
      for (int m = 0; m < 4; ++m)
        for (int r = 0; r < 4; ++r) {
          const int node = n0 + m * 16 + q * 4 + r;
          if (node < N) {
            const float v = acc2[m][t][r] + b2f;
            const float ct = tanhf(v);
            const float z = z_reg[t][m][r];
            const float xv = x[(size_t)node * HDIM + n2];
            out_upd[(size_t)node * HDIM + n2] = (1.f - z) * xv + z * ct;
          }
        }
    }
  }
}

__global__ void sentinel_kernel(float* out, int n, float val) {
  const int i = blockIdx.x * 256 + threadIdx.x;
  if (i < n) out[i] = val;
}

// ---------------------------------------------------------------------------
extern "C" void kernel_launch(void* const* d_in, const int* in_sizes, int n_in,
                              void* d_out, int out_size, void* d_ws, size_t ws_size,
                              hipStream_t stream) {
  const float* x  = (const float*)d_in[0];
  const float* xs = (const float*)d_in[1];
  const float* ef = (const float*)d_in[2];
  const int*   ei = (const int*)d_in[3];

  const int N = in_sizes[0] / HDIM;
  const int E = in_sizes[3] / 2;

  float* out = (float*)d_out;

  const int NB = (N + 255) / 256;

  const bool sizes_ok =
      n_in == 24 && NB <= 1024 &&
      in_sizes[0] == N * HDIM && in_sizes[1] == N * SDIM &&
      in_sizes[2] == E * FDIM && in_sizes[3] == 2 * E &&
      in_sizes[4] == WATT * KA && in_sizes[5] == WATT &&
      in_sizes[6] == WATT && in_sizes[7] == 1 &&
      in_sizes[12] == KG * KG && in_sizes[13] == KG &&
      in_sizes[14] == HDIM * KG && in_sizes[15] == HDIM &&
      out_size == 3 * N * HDIM + 2 * E;
  if (!sizes_ok) {
    sentinel_kernel<<<(out_size + 255) / 256, 256, 0, stream>>>(out, out_size, 777.0f);
    return;
  }

  // ws layout (u32 units):
  // pe[eA] | EdgeB[16896 u4] | NodeF[NODEF_Q u4] | xb[N*48] | xsb[N*24] |
  // fwdmb[N*48] | revmb[N*48] | tabs[N*384] (4 x N x 192 bf16) |
  // deg_d..pos_s[6N] | bsum[2048] | eidx_d[E] | eidx_s[E]
  const size_t eA = ((size_t)E + 3) & ~(size_t)3;
  const size_t needed =
      (eA + (size_t)EDGEB_Q * 4 + (size_t)NODEF_Q * 4 +
       (size_t)N * 48 + (size_t)N * 24 + 2 * (size_t)N * 48 +
       (size_t)N * 384 + 6 * (size_t)N + 2048 + 2 * (size_t)E) * 4;
  if (ws_size < needed) {
    sentinel_kernel<<<(out_size + 255) / 256, 256, 0, stream>>>(out, out_size, 12345.0f);
    return;
  }
  float* pe    = (float*)d_ws;
  uint4* EdgeB = (uint4*)((u32*)d_ws + eA);
  uint4* NodeF = EdgeB + EDGEB_Q;
  u32*   xbw   = (u32*)(NodeF + NODEF_Q);
  u32*   xsbw  = xbw + (size_t)N * 48;
  u32*   fwdmb = xsbw + (size_t)N * 24;
  u32*   revmb = fwdmb + (size_t)N * 48;
  u32*   tabs32 = revmb + (size_t)N * 48;
  u16*   tabs  = (u16*)tabs32;
  int* deg_d   = (int*)(tabs32 + (size_t)N * 384);
  int* deg_s   = deg_d + N;
  int* start_d = deg_s + N;
  int* start_s = start_d + N;
  int* pos_d   = start_s + N;
  int* pos_s   = pos_d + N;
  int* bsum_d  = pos_s + N;
  int* bsum_s  = bsum_d + 1024;
  int* eidx_d  = bsum_s + 1024;
  int* eidx_s  = eidx_d + E;

  float* out_update = out;                         // [N,96]
  float* out_fwdw   = out + (size_t)N * HDIM;      // [E]
  float* out_revw   = out_fwdw + E;                // [E]
  float* out_z      = out_revw + E;                // [N,96]
  float* out_r      = out_z + (size_t)N * HDIM;    // [N,96]

  (void)hipMemsetAsync(deg_d, 0, 2 * (size_t)N * sizeof(int), stream);

  // merged prep (edge proj/ef fragments, node W fragments, x/xs -> bf16)
  const int prep_blocks = PB_EDGE + PB_NODE + (N * 72 + 255) / 256;
  prep_all<<<prep_blocks, 256, 0, stream>>>(
      (const float*)d_in[4], (const float*)d_in[8], EdgeB,
      (const float*)d_in[12], (const float*)d_in[14],
      (const float*)d_in[16], (const float*)d_in[18],
      (const float*)d_in[20], (const float*)d_in[22], NodeF,
      x, xs, xbw, xsbw, N);

  // CSR build
  const int eblk = (E + 255) / 256;
  k_hist<<<eblk, 256, 0, stream>>>(ei, deg_d, deg_s, N, E);
  k_scan1<<<NB, 256, 0, stream>>>(deg_d, deg_s, start_d, start_s,
                                  bsum_d, bsum_s, N);
  k_scan3<<<NB, 256, 0, stream>>>(start_d, start_s, bsum_d, bsum_s,
                                  pos_d, pos_s, N);
  k_fill<<<eblk, 256, 0, stream>>>(ei, pos_d, pos_s, eidx_d, eidx_s, N, E);

  // node projection tables (4 x [N x 192] bf16)
  proj_kernel<<<(N + 63) / 64, 512, 0, stream>>>(
      xbw, xsbw, (const u16*)EdgeB, tabs, N);

  // edge scores via table gather + ef MFMA
  edge_asm<<<(E + 63) / 64, 512, 0, stream>>>(
      ef, ei, (const u16*)EdgeB, tabs,
      (const float*)d_in[5], (const float*)d_in[6], (const float*)d_in[7],
      (const float*)d_in[9], (const float*)d_in[10], (const float*)d_in[11],
      pe, out_revw, N, E);

  // gather-aggregate (both directions, one launch)
  const int ablk = (N + 7) / 8;
  k_agg_all<<<2 * ablk, 256, 0, stream>>>(
      x, ei, pe, out_revw,
      start_d, pos_d, eidx_d, start_s, pos_s, eidx_s,
      (u16*)fwdmb, (u16*)revmb, out_fwdw, N, E, ablk);

  // fused node MLPs
  const int nblk = (N + 63) / 64;
  node_fused<<<nblk, 256, 0, stream>>>(
      x, xbw, fwdmb, revmb, NodeF,
      (const float*)d_in[13], (const float*)d_in[15],
      (const float*)d_in[17], (const float*)d_in[19],
      (const float*)d_in[21], (const float*)d_in[23],
      out_r, out_z, out_update, N);
}